// Round 1
// baseline (1641.061 us; speedup 1.0000x reference)
//
#include <hip/hip_runtime.h>

#define NN 200000
#define CC 2000
#define EBN 2000000
#define ESN 40000
#define EPSA 1e-4f

__device__ __forceinline__ unsigned fenc(float f) {
    unsigned b = __float_as_uint(f);
    return (b & 0x80000000u) ? ~b : (b | 0x80000000u);
}
__device__ __forceinline__ float fdec(unsigned u) {
    return (u & 0x80000000u) ? __uint_as_float(u ^ 0x80000000u) : __uint_as_float(~u);
}

// ---------------- histogram of bip_dst ----------------
__global__ __launch_bounds__(256) void k_hist(const int* __restrict__ bdst, int* __restrict__ hist) {
    __shared__ int h[CC];
    const int t = threadIdx.x;
    for (int i = t; i < CC; i += 256) h[i] = 0;
    __syncthreads();
    for (int e = blockIdx.x * 256 + t; e < EBN; e += gridDim.x * 256)
        atomicAdd(&h[bdst[e]], 1);
    __syncthreads();
    for (int i = t; i < CC; i += 256) if (h[i]) atomicAdd(&hist[i], h[i]);
}

// ---------------- exclusive scan over C=2000 ----------------
__global__ __launch_bounds__(1024) void k_scan(const int* __restrict__ hist, int* __restrict__ offs,
                                               int* __restrict__ cursor) {
    __shared__ int buf[2][2048];
    const int t = threadIdx.x;
    buf[0][t]        = (t        < CC) ? hist[t]        : 0;
    buf[0][t + 1024] = (t + 1024 < CC) ? hist[t + 1024] : 0;
    __syncthreads();
    int pp = 0;
    for (int off = 1; off < 2048; off <<= 1) {
        const int np = pp ^ 1;
        for (int i = t; i < 2048; i += 1024) {
            int v = buf[pp][i];
            if (i >= off) v += buf[pp][i - off];
            buf[np][i] = v;
        }
        pp = np;
        __syncthreads();
    }
    for (int i = t; i < CC; i += 1024) {
        const int ex = (i == 0) ? 0 : buf[pp][i - 1];
        offs[i] = ex;
        cursor[i] = ex;
    }
}

// ---------------- node MLP + l2norm + cluster scatter ----------------
// block=256 (4 waves), 64 rows/block; lane l owns hidden j = l + 64*m (m=0..7)
__global__ __launch_bounds__(256) void k_mlp1(
    const float* __restrict__ nodes, const int* __restrict__ clusters,
    const float* __restrict__ W1, const float* __restrict__ b1,
    const float* __restrict__ g1, const float* __restrict__ be1,
    const float* __restrict__ W2, const float* __restrict__ b2,
    float* __restrict__ emb, float* __restrict__ sums, float* __restrict__ cnt) {
    __shared__ float xs[64 * 128];
    __shared__ float w2s[512 * 16];
    const int tid = threadIdx.x;
    const int row0 = blockIdx.x * 64;
    {
        const float4* src = (const float4*)(nodes + (size_t)row0 * 128);
        float4* dst = (float4*)xs;
#pragma unroll
        for (int i = 0; i < 8; ++i) dst[tid + 256 * i] = src[tid + 256 * i];
        const float4* w2src = (const float4*)W2;
        float4* w2dst = (float4*)w2s;
#pragma unroll
        for (int i = 0; i < 8; ++i) {
            const int i4 = tid + 256 * i;
            const int row = i4 >> 2, q = i4 & 3;
            w2dst[(row << 2) | (q ^ ((row >> 1) & 3))] = w2src[i4];  // bank swizzle
        }
    }
    __syncthreads();
    const int wv = tid >> 6, l = tid & 63;
    const int rbase = wv * 16;
    float acc[16][8];
#pragma unroll
    for (int r = 0; r < 16; ++r)
#pragma unroll
        for (int m = 0; m < 8; ++m) acc[r][m] = 0.f;

    const float4* xs4 = (const float4*)xs;
    for (int k4 = 0; k4 < 32; ++k4) {
        float wr[4][8];
#pragma unroll
        for (int kk = 0; kk < 4; ++kk) {
            const float* wp = W1 + (k4 * 4 + kk) * 512 + l;
#pragma unroll
            for (int m = 0; m < 8; ++m) wr[kk][m] = wp[m * 64];
        }
#pragma unroll
        for (int r = 0; r < 16; ++r) {
            const float4 x = xs4[(rbase + r) * 32 + k4];
#pragma unroll
            for (int m = 0; m < 8; ++m) {
                acc[r][m] = fmaf(x.x, wr[0][m], acc[r][m]);
                acc[r][m] = fmaf(x.y, wr[1][m], acc[r][m]);
                acc[r][m] = fmaf(x.z, wr[2][m], acc[r][m]);
                acc[r][m] = fmaf(x.w, wr[3][m], acc[r][m]);
            }
        }
    }

    float vb1[8], vg1[8], vbe1[8];
#pragma unroll
    for (int m = 0; m < 8; ++m) {
        vb1[m] = b1[l + 64 * m];
        vg1[m] = g1[l + 64 * m];
        vbe1[m] = be1[l + 64 * m];
    }
    float b2v[16];
#pragma unroll
    for (int o = 0; o < 16; ++o) b2v[o] = b2[o];
    const int qsw = (l >> 1) & 3;

    for (int r = 0; r < 16; ++r) {
        const int row = row0 + rbase + r;
        float h[8], s = 0.f, sq = 0.f;
#pragma unroll
        for (int m = 0; m < 8; ++m) {
            h[m] = acc[r][m] + vb1[m];
            s += h[m];
            sq += h[m] * h[m];
        }
#pragma unroll
        for (int off = 1; off < 64; off <<= 1) {
            s += __shfl_xor(s, off, 64);
            sq += __shfl_xor(sq, off, 64);
        }
        const float mean = s * (1.f / 512.f);
        const float inv = rsqrtf(sq * (1.f / 512.f) - mean * mean + 1e-5f);
        float p[16];
#pragma unroll
        for (int o = 0; o < 16; ++o) p[o] = 0.f;
#pragma unroll
        for (int m = 0; m < 8; ++m) {
            const float rv = fmaxf((h[m] - mean) * inv * vg1[m] + vbe1[m], 0.f);
            const float4* wrow = (const float4*)w2s + (l + 64 * m) * 4;
#pragma unroll
            for (int q = 0; q < 4; ++q) {
                const float4 wq = wrow[q ^ qsw];
                p[q * 4 + 0] = fmaf(rv, wq.x, p[q * 4 + 0]);
                p[q * 4 + 1] = fmaf(rv, wq.y, p[q * 4 + 1]);
                p[q * 4 + 2] = fmaf(rv, wq.z, p[q * 4 + 2]);
                p[q * 4 + 3] = fmaf(rv, wq.w, p[q * 4 + 3]);
            }
        }
#pragma unroll
        for (int o = 0; o < 16; ++o) {
#pragma unroll
            for (int off = 1; off < 64; off <<= 1) p[o] += __shfl_xor(p[o], off, 64);
        }
        float ss = 0.f, sel = 0.f;
#pragma unroll
        for (int o = 0; o < 16; ++o) {
            const float vo = p[o] + b2v[o];
            ss += vo * vo;
            if (l == o) sel = vo;
        }
        const float invn = 1.f / fmaxf(sqrtf(ss), 1e-12f);
        if (l < 16) {
            const float ev = sel * invn;
            emb[(size_t)row * 16 + l] = ev;
            const int cl = clusters[row];
            if (cl >= 0) {
                atomicAdd(&sums[cl * 16 + l], ev);
                if (l == 0) atomicAdd(&cnt[cl], 1.f);
            }
        }
    }
}

// ---------------- cluster means + l2norm ----------------
__global__ __launch_bounds__(256) void k_means(const float* __restrict__ sums, const float* __restrict__ cnt,
                                               float* __restrict__ means) {
    const int t = blockIdx.x * 256 + threadIdx.x;
    const int c = t >> 4;
    const float v = sums[t] / fmaxf(cnt[c], 1.f);
    float sq = v * v;
#pragma unroll
    for (int off = 1; off < 16; off <<= 1) sq += __shfl_xor(sq, off, 16);
    means[t] = v / fmaxf(sqrtf(sq), 1e-12f);
}

// ---------------- bipartite attention pass A: dots + seg max/min ----------------
__global__ __launch_bounds__(256) void k_bip_dot(const int* __restrict__ src, const int* __restrict__ dst,
                                                 const float* __restrict__ emb, const float* __restrict__ means,
                                                 float* __restrict__ att, unsigned* __restrict__ amax,
                                                 unsigned* __restrict__ amin) {
    const int e = blockIdx.x * 256 + threadIdx.x;
    if (e >= EBN) return;
    const int s = src[e], d = dst[e];
    const float4* ev = (const float4*)(emb + (size_t)s * 16);
    const float4* mv = (const float4*)(means + (size_t)d * 16);
    float dot = 0.f;
#pragma unroll
    for (int q = 0; q < 4; ++q) {
        const float4 a = ev[q], b = mv[q];
        dot += a.x * b.x + a.y * b.y + a.z * b.z + a.w * b.w;
    }
    att[e] = dot;
    const unsigned enc = fenc(dot);
    atomicMax(&amax[s], enc);
    atomicMin(&amin[s], enc);
}

// ---------------- pass B: exp + seg sum ----------------
__global__ __launch_bounds__(256) void k_bip_exp(const int* __restrict__ src, float* __restrict__ att,
                                                 const unsigned* __restrict__ amax,
                                                 const unsigned* __restrict__ amin, float* __restrict__ asum) {
    const int e = blockIdx.x * 256 + threadIdx.x;
    if (e >= EBN) return;
    const int s = src[e];
    const float mx = fdec(amax[s]), mn = fdec(amin[s]);
    const float a = expf(2.f * (att[e] - mn) / (EPSA + (mx - mn)));
    att[e] = a;
    atomicAdd(&asum[s], a);
}

// ---------------- pass C: normalize + counting-sort scatter ----------------
__global__ __launch_bounds__(256) void k_bip_scatter(const int* __restrict__ src, const int* __restrict__ dst,
                                                     float* __restrict__ att, const float* __restrict__ asum,
                                                     int* __restrict__ cursor, int* __restrict__ src_sorted,
                                                     float* __restrict__ w_sorted) {
    const int e = blockIdx.x * 256 + threadIdx.x;
    if (e >= EBN) return;
    const int s = src[e], d = dst[e];
    const float w = att[e] / (EPSA + asum[s]);
    att[e] = w;
    const int pos = atomicAdd(&cursor[d], 1);
    src_sorted[pos] = s;
    w_sorted[pos] = w;
}

// ---------------- supernode accumulation (sorted, no atomics) ----------------
__global__ __launch_bounds__(128) void k_supernode(const int* __restrict__ src_sorted,
                                                   const float* __restrict__ w_sorted,
                                                   const int* __restrict__ offs, const int* __restrict__ hist,
                                                   const float* __restrict__ nodes, float* __restrict__ out_sn) {
    const int c = blockIdx.x, t = threadIdx.x;
    const int base = offs[c], n = hist[c];
    __shared__ int ssm[256];
    __shared__ float swm[256];
    float a0 = 0.f, a1 = 0.f, a2 = 0.f, a3 = 0.f;
    for (int i0 = 0; i0 < n; i0 += 256) {
        const int m = min(256, n - i0);
        for (int i = t; i < m; i += 128) {
            ssm[i] = src_sorted[base + i0 + i];
            swm[i] = w_sorted[base + i0 + i];
        }
        __syncthreads();
        int i = 0;
        for (; i + 4 <= m; i += 4) {
            a0 = fmaf(swm[i + 0], nodes[(size_t)ssm[i + 0] * 128 + t], a0);
            a1 = fmaf(swm[i + 1], nodes[(size_t)ssm[i + 1] * 128 + t], a1);
            a2 = fmaf(swm[i + 2], nodes[(size_t)ssm[i + 2] * 128 + t], a2);
            a3 = fmaf(swm[i + 3], nodes[(size_t)ssm[i + 3] * 128 + t], a3);
        }
        for (; i < m; ++i) a0 = fmaf(swm[i], nodes[(size_t)ssm[i] * 128 + t], a0);
        __syncthreads();
    }
    out_sn[c * 128 + t] = ((a0 + a1) + (a2 + a3));
}

// ---------------- supergraph attention ----------------
__global__ __launch_bounds__(256) void k_sup_dot(const int* __restrict__ ss, const int* __restrict__ sd,
                                                 const float* __restrict__ means, float* __restrict__ satt,
                                                 unsigned* __restrict__ smax, unsigned* __restrict__ smin) {
    const int e = blockIdx.x * 256 + threadIdx.x;
    if (e >= ESN) return;
    const int s = ss[e], d = sd[e];
    const float4* av = (const float4*)(means + (size_t)s * 16);
    const float4* bv = (const float4*)(means + (size_t)d * 16);
    float dot = 0.f;
#pragma unroll
    for (int q = 0; q < 4; ++q) {
        const float4 a = av[q], b = bv[q];
        dot += a.x * b.x + a.y * b.y + a.z * b.z + a.w * b.w;
    }
    satt[e] = dot;
    const unsigned enc = fenc(dot);
    atomicMax(&smax[d], enc);
    atomicMin(&smin[d], enc);
}

__global__ __launch_bounds__(256) void k_sup_tanh(const int* __restrict__ sd, float* __restrict__ satt,
                                                  const unsigned* __restrict__ smax,
                                                  const unsigned* __restrict__ smin) {
    const int e = blockIdx.x * 256 + threadIdx.x;
    if (e >= ESN) return;
    const int d = sd[e];
    const float mx = fdec(smax[d]), mn = fdec(smin[d]);
    satt[e] = tanhf(2.f * (satt[e] - mn) / (EPSA + (mx - mn)));
}

// ---------------- superedge encoder: [ES,256]->512 LN relu ->128 LN relu ----------------
__global__ __launch_bounds__(256) void k_edge_mlp(
    const int* __restrict__ esv, const int* __restrict__ edv, const float* __restrict__ sn,
    const float* __restrict__ W1, const float* __restrict__ b1, const float* __restrict__ g1,
    const float* __restrict__ be1, const float* __restrict__ W2, const float* __restrict__ b2,
    const float* __restrict__ g2, const float* __restrict__ be2, float* __restrict__ out_se) {
    __shared__ float lds[64 * 256];  // phase1: x[64][256]; phase3: h[32][512]
    const int tid = threadIdx.x;
    const int e0 = blockIdx.x * 64;
    {
        float4* dst = (float4*)lds;
#pragma unroll
        for (int i = 0; i < 16; ++i) {
            const int f = tid + 256 * i;
            const int r = f >> 6, q = f & 63;
            const int e = e0 + r;
            const int node = (q < 32) ? esv[e] : edv[e];
            dst[f] = ((const float4*)(sn + (size_t)node * 128))[q & 31];
        }
    }
    __syncthreads();
    const int wv = tid >> 6, l = tid & 63;
    const int rbase = wv * 16;
    float acc[16][8];
#pragma unroll
    for (int r = 0; r < 16; ++r)
#pragma unroll
        for (int m = 0; m < 8; ++m) acc[r][m] = 0.f;

    const float4* xs4 = (const float4*)lds;
    for (int k4 = 0; k4 < 64; ++k4) {
        float wr[4][8];
#pragma unroll
        for (int kk = 0; kk < 4; ++kk) {
            const float* wp = W1 + (k4 * 4 + kk) * 512 + l;
#pragma unroll
            for (int m = 0; m < 8; ++m) wr[kk][m] = wp[m * 64];
        }
#pragma unroll
        for (int r = 0; r < 16; ++r) {
            const float4 x = xs4[(rbase + r) * 64 + k4];
#pragma unroll
            for (int m = 0; m < 8; ++m) {
                acc[r][m] = fmaf(x.x, wr[0][m], acc[r][m]);
                acc[r][m] = fmaf(x.y, wr[1][m], acc[r][m]);
                acc[r][m] = fmaf(x.z, wr[2][m], acc[r][m]);
                acc[r][m] = fmaf(x.w, wr[3][m], acc[r][m]);
            }
        }
    }
    {
        float vb1[8], vg1[8], vbe1[8];
#pragma unroll
        for (int m = 0; m < 8; ++m) {
            vb1[m] = b1[l + 64 * m];
            vg1[m] = g1[l + 64 * m];
            vbe1[m] = be1[l + 64 * m];
        }
        for (int r = 0; r < 16; ++r) {
            float h[8], s = 0.f, sq = 0.f;
#pragma unroll
            for (int m = 0; m < 8; ++m) {
                h[m] = acc[r][m] + vb1[m];
                s += h[m];
                sq += h[m] * h[m];
            }
#pragma unroll
            for (int off = 1; off < 64; off <<= 1) {
                s += __shfl_xor(s, off, 64);
                sq += __shfl_xor(sq, off, 64);
            }
            const float mean = s * (1.f / 512.f);
            const float inv = rsqrtf(sq * (1.f / 512.f) - mean * mean + 1e-5f);
#pragma unroll
            for (int m = 0; m < 8; ++m)
                acc[r][m] = fmaxf((h[m] - mean) * inv * vg1[m] + vbe1[m], 0.f);
        }
    }
    __syncthreads();  // x tile fully consumed

    const int o8 = (tid & 15) * 8;
    const int rl = (tid >> 4) * 2;
    float vb2[8], vg2[8], vbe2[8];
#pragma unroll
    for (int m = 0; m < 8; ++m) {
        vb2[m] = b2[o8 + m];
        vg2[m] = g2[o8 + m];
        vbe2[m] = be2[o8 + m];
    }

    for (int half = 0; half < 2; ++half) {
        if ((wv >> 1) == half) {
            const int rloc = (wv & 1) * 16;
#pragma unroll
            for (int r = 0; r < 16; ++r)
#pragma unroll
                for (int m = 0; m < 8; ++m) lds[(rloc + r) * 512 + l + 64 * m] = acc[r][m];
        }
        __syncthreads();
        float a2[2][8];
#pragma unroll
        for (int rr = 0; rr < 2; ++rr)
#pragma unroll
            for (int m = 0; m < 8; ++m) a2[rr][m] = 0.f;
        for (int j = 0; j < 512; ++j) {
            const float4* wv4 = (const float4*)(W2 + j * 128 + o8);
            const float4 wA = wv4[0], wB = wv4[1];
            const float h0 = lds[rl * 512 + j];
            const float h1 = lds[(rl + 1) * 512 + j];
            a2[0][0] = fmaf(h0, wA.x, a2[0][0]);
            a2[0][1] = fmaf(h0, wA.y, a2[0][1]);
            a2[0][2] = fmaf(h0, wA.z, a2[0][2]);
            a2[0][3] = fmaf(h0, wA.w, a2[0][3]);
            a2[0][4] = fmaf(h0, wB.x, a2[0][4]);
            a2[0][5] = fmaf(h0, wB.y, a2[0][5]);
            a2[0][6] = fmaf(h0, wB.z, a2[0][6]);
            a2[0][7] = fmaf(h0, wB.w, a2[0][7]);
            a2[1][0] = fmaf(h1, wA.x, a2[1][0]);
            a2[1][1] = fmaf(h1, wA.y, a2[1][1]);
            a2[1][2] = fmaf(h1, wA.z, a2[1][2]);
            a2[1][3] = fmaf(h1, wA.w, a2[1][3]);
            a2[1][4] = fmaf(h1, wB.x, a2[1][4]);
            a2[1][5] = fmaf(h1, wB.y, a2[1][5]);
            a2[1][6] = fmaf(h1, wB.z, a2[1][6]);
            a2[1][7] = fmaf(h1, wB.w, a2[1][7]);
        }
#pragma unroll
        for (int rr = 0; rr < 2; ++rr) {
            float s = 0.f, sq = 0.f;
#pragma unroll
            for (int m = 0; m < 8; ++m) {
                const float tv = a2[rr][m] + vb2[m];
                s += tv;
                sq += tv * tv;
            }
#pragma unroll
            for (int off = 1; off < 16; off <<= 1) {
                s += __shfl_xor(s, off, 16);
                sq += __shfl_xor(sq, off, 16);
            }
            const float mean = s * (1.f / 128.f);
            const float inv = rsqrtf(sq * (1.f / 128.f) - mean * mean + 1e-5f);
            float o_[8];
#pragma unroll
            for (int m = 0; m < 8; ++m)
                o_[m] = fmaxf((a2[rr][m] + vb2[m] - mean) * inv * vg2[m] + vbe2[m], 0.f);
            float4* op = (float4*)(out_se + (size_t)(e0 + half * 32 + rl + rr) * 128 + o8);
            op[0] = make_float4(o_[0], o_[1], o_[2], o_[3]);
            op[1] = make_float4(o_[4], o_[5], o_[6], o_[7]);
        }
        __syncthreads();  // before next half overwrites lds
    }
}

extern "C" void kernel_launch(void* const* d_in, const int* in_sizes, int n_in,
                              void* d_out, int out_size, void* d_ws, size_t ws_size,
                              hipStream_t stream) {
    const float* nodes = (const float*)d_in[0];
    const int* clusters = (const int*)d_in[1];
    const int* bsrc = (const int*)d_in[2];
    const int* bdst = (const int*)d_in[3];
    const int* susrc = (const int*)d_in[4];
    const int* sudst = (const int*)d_in[5];
    const float* cW1 = (const float*)d_in[6];
    const float* cb1 = (const float*)d_in[7];
    const float* cg1 = (const float*)d_in[8];
    const float* cbe1 = (const float*)d_in[9];
    const float* cW2 = (const float*)d_in[10];
    const float* cb2 = (const float*)d_in[11];
    const float* eW1 = (const float*)d_in[12];
    const float* eb1 = (const float*)d_in[13];
    const float* eg1 = (const float*)d_in[14];
    const float* ebe1 = (const float*)d_in[15];
    const float* eW2 = (const float*)d_in[16];
    const float* eb2 = (const float*)d_in[17];
    const float* eg2 = (const float*)d_in[18];
    const float* ebe2 = (const float*)d_in[19];

    float* out_sn = (float*)d_out;
    float* out_se = out_sn + (size_t)CC * 128;
    float* out_bip = out_se + (size_t)ESN * 128;
    float* out_satt = out_bip + EBN;

    // workspace layout (u32 units)
    float* sums = (float*)d_ws;                            // 32000
    float* cnt = sums + 32000;                             // 2000
    int* hist = (int*)(cnt + 2000);                        // 2000
    unsigned* smax = (unsigned*)(hist + 2000);             // 2000
    float* asum = (float*)(smax + 2000);                   // 200000
    unsigned* amax = (unsigned*)(asum + 200000);           // 200000
    unsigned* amin = amax + 200000;                        // 200000
    unsigned* smin = amin + 200000;                        // 2000
    float* emb = (float*)(smin + 2000);                    // 3200000
    float* means = emb + 3200000;                          // 32000
    int* offs = (int*)(means + 32000);                     // 2000
    int* cursor = offs + 2000;                             // 2000
    int* src_sorted = cursor + 2000;                       // 2000000
    float* w_sorted = (float*)(src_sorted + 2000000);      // 2000000

    // init: [sums|cnt|hist|smax|asum|amax] = 0 ; [amin|smin] = 0xFF
    hipMemsetAsync(sums, 0, (size_t)(32000 + 2000 + 2000 + 2000 + 200000 + 200000) * 4, stream);
    hipMemsetAsync(amin, 0xFF, (size_t)(200000 + 2000) * 4, stream);

    k_hist<<<256, 256, 0, stream>>>(bdst, hist);
    k_scan<<<1, 1024, 0, stream>>>(hist, offs, cursor);
    k_mlp1<<<NN / 64, 256, 0, stream>>>(nodes, clusters, cW1, cb1, cg1, cbe1, cW2, cb2, emb, sums, cnt);
    k_means<<<(CC * 16) / 256, 256, 0, stream>>>(sums, cnt, means);
    k_bip_dot<<<(EBN + 255) / 256, 256, 0, stream>>>(bsrc, bdst, emb, means, out_bip, amax, amin);
    k_bip_exp<<<(EBN + 255) / 256, 256, 0, stream>>>(bsrc, out_bip, amax, amin, asum);
    k_bip_scatter<<<(EBN + 255) / 256, 256, 0, stream>>>(bsrc, bdst, out_bip, asum, cursor, src_sorted, w_sorted);
    k_supernode<<<CC, 128, 0, stream>>>(src_sorted, w_sorted, offs, hist, nodes, out_sn);
    k_sup_dot<<<(ESN + 255) / 256, 256, 0, stream>>>(susrc, sudst, means, out_satt, smax, smin);
    k_sup_tanh<<<(ESN + 255) / 256, 256, 0, stream>>>(sudst, out_satt, smax, smin);
    k_edge_mlp<<<ESN / 64, 256, 0, stream>>>(susrc, sudst, out_sn, eW1, eb1, eg1, ebe1, eW2, eb2, eg2, ebe2, out_se);
}

// Round 3
// 1288.143 us; speedup vs baseline: 1.2740x; 1.2740x over previous
//
#include <hip/hip_runtime.h>

#define NN 200000
#define CC 2000
#define EBN 2000000
#define ESN 40000
#define EPSA 1e-4f

typedef unsigned short ushort_t;
typedef float f32x4 __attribute__((ext_vector_type(4)));
typedef __bf16 bf16x8 __attribute__((ext_vector_type(8)));

__device__ __forceinline__ unsigned fenc(float f) {
    unsigned b = __float_as_uint(f);
    return (b & 0x80000000u) ? ~b : (b | 0x80000000u);
}
__device__ __forceinline__ float fdec(unsigned u) {
    return (u & 0x80000000u) ? __uint_as_float(u ^ 0x80000000u) : __uint_as_float(~u);
}
__device__ __forceinline__ unsigned f2bf(float f) {  // RNE f32 -> bf16 bits
    unsigned u = __float_as_uint(f);
    return (u + 0x7fffu + ((u >> 16) & 1u)) >> 16;
}
__device__ __forceinline__ void split2(float f, unsigned& hi, unsigned& lo) {
    hi = f2bf(f);
    const float fh = __uint_as_float(hi << 16);
    lo = f2bf(f - fh);
}

// ---------------- weight convert: cW1 -> hi/lo bf16 [N][K]; eW1,eW2 -> bf16 [N][K] ----------------
__global__ __launch_bounds__(256) void k_conv(const float* __restrict__ cW1, const float* __restrict__ eW1,
                                              const float* __restrict__ eW2,
                                              ushort_t* __restrict__ cW1hi, ushort_t* __restrict__ cW1lo,
                                              ushort_t* __restrict__ eW1t, ushort_t* __restrict__ eW2t) {
    int id = blockIdx.x * 256 + threadIdx.x;
    if (id < 65536) {
        const int n = id >> 7, k = id & 127;
        unsigned hi, lo;
        split2(cW1[k * 512 + n], hi, lo);
        cW1hi[id] = (ushort_t)hi;
        cW1lo[id] = (ushort_t)lo;
        return;
    }
    id -= 65536;
    if (id < 131072) { const int n = id >> 8, k = id & 255; eW1t[id] = (ushort_t)f2bf(eW1[k * 512 + n]); return; }
    id -= 131072;
    if (id < 65536) { const int n = id >> 9, k = id & 511; eW2t[id] = (ushort_t)f2bf(eW2[k * 128 + n]); return; }
}

// ---------------- histogram of bip_dst ----------------
__global__ __launch_bounds__(256) void k_hist(const int* __restrict__ bdst, int* __restrict__ hist) {
    __shared__ int h[CC];
    const int t = threadIdx.x;
    for (int i = t; i < CC; i += 256) h[i] = 0;
    __syncthreads();
    for (int e = blockIdx.x * 256 + t; e < EBN; e += gridDim.x * 256)
        atomicAdd(&h[bdst[e]], 1);
    __syncthreads();
    for (int i = t; i < CC; i += 256) if (h[i]) atomicAdd(&hist[i], h[i]);
}

// ---------------- exclusive scan over C=2000 ----------------
__global__ __launch_bounds__(1024) void k_scan(const int* __restrict__ hist, int* __restrict__ offs,
                                               int* __restrict__ cursor) {
    __shared__ int buf[2][2048];
    const int t = threadIdx.x;
    buf[0][t]        = (t        < CC) ? hist[t]        : 0;
    buf[0][t + 1024] = (t + 1024 < CC) ? hist[t + 1024] : 0;
    __syncthreads();
    int pp = 0;
    for (int off = 1; off < 2048; off <<= 1) {
        const int np = pp ^ 1;
        for (int i = t; i < 2048; i += 1024) {
            int v = buf[pp][i];
            if (i >= off) v += buf[pp][i - off];
            buf[np][i] = v;
        }
        pp = np;
        __syncthreads();
    }
    for (int i = t; i < CC; i += 1024) {
        const int ex = (i == 0) ? 0 : buf[pp][i - 1];
        offs[i] = ex;
        cursor[i] = ex;
    }
}

// ---------------- node MLP: split-bf16 MFMA phase1 + fp32 VALU phase2 ----------------
// 32 rows/block, 4 waves; wave w owns hidden cols [128w,128w+128)
__global__ __launch_bounds__(256) void k_mlp1(
    const float* __restrict__ nodes, const int* __restrict__ clusters,
    const ushort_t* __restrict__ W1hi, const ushort_t* __restrict__ W1lo, const float* __restrict__ b1,
    const float* __restrict__ g1, const float* __restrict__ be1,
    const float* __restrict__ W2, const float* __restrict__ b2,
    float* __restrict__ emb, float* __restrict__ sums, float* __restrict__ cnt) {
    __shared__ ushort_t Xhi[32 * 128];  // 8 KB, XOR-swizzled
    __shared__ ushort_t Xlo[32 * 128];  // 8 KB, XOR-swizzled
    __shared__ float redS[4][32], redQ[4][32];
    __shared__ float Cbuf[4][32][16];
    const int tid = threadIdx.x;
    const int row0 = blockIdx.x * 32;

    // stage X -> (hi,lo) bf16 LDS (swizzled)
#pragma unroll
    for (int i = 0; i < 2; ++i) {
        const int c = tid + 256 * i;
        const int row = c >> 4, c8 = c & 15;
        const float4* gp = (const float4*)(nodes + (size_t)(row0 + row) * 128 + c8 * 8);
        const float4 u = gp[0], v = gp[1];
        unsigned h0, l0, h1, l1, h2, l2, h3, l3, h4, l4, h5, l5, h6, l6, h7, l7;
        split2(u.x, h0, l0); split2(u.y, h1, l1); split2(u.z, h2, l2); split2(u.w, h3, l3);
        split2(v.x, h4, l4); split2(v.y, h5, l5); split2(v.z, h6, l6); split2(v.w, h7, l7);
        uint4 pkh, pkl;
        pkh.x = h0 | (h1 << 16); pkh.y = h2 | (h3 << 16); pkh.z = h4 | (h5 << 16); pkh.w = h6 | (h7 << 16);
        pkl.x = l0 | (l1 << 16); pkl.y = l2 | (l3 << 16); pkl.z = l4 | (l5 << 16); pkl.w = l6 | (l7 << 16);
        const int byte = row * 256 + ((c8 * 16) ^ ((row & 7) << 4));
        *(uint4*)((char*)Xhi + byte) = pkh;
        *(uint4*)((char*)Xlo + byte) = pkl;
    }
    __syncthreads();

    const int wv = tid >> 6, l = tid & 63;
    const int q = l >> 4, c16 = l & 15;
    const int wcol0 = wv * 128;

    f32x4 acc[2][8];
#pragma unroll
    for (int mt = 0; mt < 2; ++mt)
#pragma unroll
        for (int nt = 0; nt < 8; ++nt) acc[mt][nt] = (f32x4){0.f, 0.f, 0.f, 0.f};

    // phase 1: H = X @ W1 with 3-term split (error ~2^-17)
#pragma unroll
    for (int ks = 0; ks < 4; ++ks) {
        bf16x8 ah[2], al[2];
#pragma unroll
        for (int mt = 0; mt < 2; ++mt) {
            const int row = 16 * mt + c16;
            const int byte = row * 256 + ((64 * ks + 16 * q) ^ ((row & 7) << 4));
            ah[mt] = __builtin_bit_cast(bf16x8, *(const uint4*)((const char*)Xhi + byte));
            al[mt] = __builtin_bit_cast(bf16x8, *(const uint4*)((const char*)Xlo + byte));
        }
#pragma unroll
        for (int nt = 0; nt < 8; ++nt) {
            const int n = wcol0 + 16 * nt + c16;
            const bf16x8 bhi = __builtin_bit_cast(bf16x8, *(const uint4*)(W1hi + n * 128 + 32 * ks + 8 * q));
            const bf16x8 blo = __builtin_bit_cast(bf16x8, *(const uint4*)(W1lo + n * 128 + 32 * ks + 8 * q));
#pragma unroll
            for (int mt = 0; mt < 2; ++mt) {
                acc[mt][nt] = __builtin_amdgcn_mfma_f32_16x16x32_bf16(ah[mt], bhi, acc[mt][nt], 0, 0, 0);
                acc[mt][nt] = __builtin_amdgcn_mfma_f32_16x16x32_bf16(al[mt], bhi, acc[mt][nt], 0, 0, 0);
                acc[mt][nt] = __builtin_amdgcn_mfma_f32_16x16x32_bf16(ah[mt], blo, acc[mt][nt], 0, 0, 0);
            }
        }
    }

    // phase 1.5: +b1, LN(512), ReLU (all fp32) -> rv kept in acc
    float b1v[8], g1v[8], bev[8];
#pragma unroll
    for (int nt = 0; nt < 8; ++nt) {
        const int col = wcol0 + 16 * nt + c16;
        b1v[nt] = b1[col]; g1v[nt] = g1[col]; bev[nt] = be1[col];
    }
    float sS[2][4], sQ[2][4];
#pragma unroll
    for (int mt = 0; mt < 2; ++mt)
#pragma unroll
        for (int r = 0; r < 4; ++r) {
            float s = 0.f, qq = 0.f;
#pragma unroll
            for (int nt = 0; nt < 8; ++nt) {
                const float h = acc[mt][nt][r] + b1v[nt];
                acc[mt][nt][r] = h;
                s += h; qq += h * h;
            }
#pragma unroll
            for (int off = 1; off < 16; off <<= 1) {
                s += __shfl_xor(s, off);
                qq += __shfl_xor(qq, off);
            }
            sS[mt][r] = s; sQ[mt][r] = qq;
        }
    if (c16 == 0) {
#pragma unroll
        for (int mt = 0; mt < 2; ++mt)
#pragma unroll
            for (int r = 0; r < 4; ++r) {
                const int row = 16 * mt + 4 * q + r;
                redS[wv][row] = sS[mt][r];
                redQ[wv][row] = sQ[mt][r];
            }
    }
    __syncthreads();
#pragma unroll
    for (int mt = 0; mt < 2; ++mt)
#pragma unroll
        for (int r = 0; r < 4; ++r) {
            const int row = 16 * mt + 4 * q + r;
            const float S = redS[0][row] + redS[1][row] + redS[2][row] + redS[3][row];
            const float Q = redQ[0][row] + redQ[1][row] + redQ[2][row] + redQ[3][row];
            const float m_ = S * (1.f / 512.f);
            const float iv = rsqrtf(Q * (1.f / 512.f) - m_ * m_ + 1e-5f);
#pragma unroll
            for (int nt = 0; nt < 8; ++nt)
                acc[mt][nt][r] = fmaxf((acc[mt][nt][r] - m_) * iv * g1v[nt] + bev[nt], 0.f);
        }

    // phase 2: emb = relu'd H @ W2, exact fp32 on VALU from registers.
    // Each lane: 8 rows x 8 outs over its 8 cols; butterfly-reduce over the 16 col-lanes.
#pragma unroll
    for (int half = 0; half < 2; ++half) {
        float p[8][8];
#pragma unroll
        for (int rw = 0; rw < 8; ++rw)
#pragma unroll
            for (int o = 0; o < 8; ++o) p[rw][o] = 0.f;
#pragma unroll
        for (int nt = 0; nt < 8; ++nt) {
            const int col = wcol0 + 16 * nt + c16;
            const float4 wA = *(const float4*)(W2 + col * 16 + half * 8);
            const float4 wB = *(const float4*)(W2 + col * 16 + half * 8 + 4);
#pragma unroll
            for (int mt = 0; mt < 2; ++mt)
#pragma unroll
                for (int r = 0; r < 4; ++r) {
                    const float rv = acc[mt][nt][r];
                    float* pr = p[mt * 4 + r];
                    pr[0] = fmaf(rv, wA.x, pr[0]);
                    pr[1] = fmaf(rv, wA.y, pr[1]);
                    pr[2] = fmaf(rv, wA.z, pr[2]);
                    pr[3] = fmaf(rv, wA.w, pr[3]);
                    pr[4] = fmaf(rv, wB.x, pr[4]);
                    pr[5] = fmaf(rv, wB.y, pr[5]);
                    pr[6] = fmaf(rv, wB.z, pr[6]);
                    pr[7] = fmaf(rv, wB.w, pr[7]);
                }
        }
#pragma unroll
        for (int rw = 0; rw < 8; ++rw)
#pragma unroll
            for (int o = 0; o < 8; ++o) {
#pragma unroll
                for (int off = 1; off < 16; off <<= 1) p[rw][o] += __shfl_xor(p[rw][o], off);
            }
        if (c16 < 8) {
#pragma unroll
            for (int rw = 0; rw < 8; ++rw) {
                float s_ = p[rw][0];
#pragma unroll
                for (int o = 1; o < 8; ++o) s_ = (c16 == o) ? p[rw][o] : s_;
                const int row = 16 * (rw >> 2) + 4 * q + (rw & 3);
                Cbuf[wv][row][half * 8 + c16] = s_;
            }
        }
    }
    __syncthreads();

    // final: cross-wave K-reduce, +b2, l2norm, store + cluster atomics
#pragma unroll
    for (int rep = 0; rep < 2; ++rep) {
        const int slot = tid + 256 * rep;
        const int row = slot >> 4, col = slot & 15;
        float val = Cbuf[0][row][col] + Cbuf[1][row][col] + Cbuf[2][row][col] + Cbuf[3][row][col] + b2[col];
        float ss = val * val;
#pragma unroll
        for (int off = 1; off < 16; off <<= 1) ss += __shfl_xor(ss, off);
        const float ev = val / fmaxf(sqrtf(ss), 1e-12f);
        const int grow = row0 + row;
        emb[(size_t)grow * 16 + col] = ev;
        const int cl = clusters[grow];
        if (cl >= 0) {
            atomicAdd(&sums[cl * 16 + col], ev);
            if (col == 0) atomicAdd(&cnt[cl], 1.f);
        }
    }
}

// ---------------- cluster means + l2norm ----------------
__global__ __launch_bounds__(256) void k_means(const float* __restrict__ sums, const float* __restrict__ cnt,
                                               float* __restrict__ means) {
    const int t = blockIdx.x * 256 + threadIdx.x;
    const int c = t >> 4;
    const float v = sums[t] / fmaxf(cnt[c], 1.f);
    float sq = v * v;
#pragma unroll
    for (int off = 1; off < 16; off <<= 1) sq += __shfl_xor(sq, off, 16);
    means[t] = v / fmaxf(sqrtf(sq), 1e-12f);
}

// ---------------- bipartite attention pass A: dots + seg max/min ----------------
__global__ __launch_bounds__(256) void k_bip_dot(const int* __restrict__ src, const int* __restrict__ dst,
                                                 const float* __restrict__ emb, const float* __restrict__ means,
                                                 float* __restrict__ att, unsigned* __restrict__ amax,
                                                 unsigned* __restrict__ amin) {
    const int e = blockIdx.x * 256 + threadIdx.x;
    if (e >= EBN) return;
    const int s = src[e], d = dst[e];
    const float4* ev = (const float4*)(emb + (size_t)s * 16);
    const float4* mv = (const float4*)(means + (size_t)d * 16);
    float dot = 0.f;
#pragma unroll
    for (int q = 0; q < 4; ++q) {
        const float4 a = ev[q], b = mv[q];
        dot += a.x * b.x + a.y * b.y + a.z * b.z + a.w * b.w;
    }
    att[e] = dot;
    const unsigned enc = fenc(dot);
    atomicMax(&amax[s], enc);
    atomicMin(&amin[s], enc);
}

// ---------------- pass B: exp + seg sum ----------------
__global__ __launch_bounds__(256) void k_bip_exp(const int* __restrict__ src, float* __restrict__ att,
                                                 const unsigned* __restrict__ amax,
                                                 const unsigned* __restrict__ amin, float* __restrict__ asum) {
    const int e = blockIdx.x * 256 + threadIdx.x;
    if (e >= EBN) return;
    const int s = src[e];
    const float mx = fdec(amax[s]), mn = fdec(amin[s]);
    const float a = expf(2.f * (att[e] - mn) / (EPSA + (mx - mn)));
    att[e] = a;
    atomicAdd(&asum[s], a);
}

// ---------------- pass C: normalize + counting-sort scatter ----------------
__global__ __launch_bounds__(256) void k_bip_scatter(const int* __restrict__ src, const int* __restrict__ dst,
                                                     float* __restrict__ att, const float* __restrict__ asum,
                                                     int* __restrict__ cursor, int* __restrict__ src_sorted,
                                                     float* __restrict__ w_sorted) {
    const int e = blockIdx.x * 256 + threadIdx.x;
    if (e >= EBN) return;
    const int s = src[e], d = dst[e];
    const float w = att[e] / (EPSA + asum[s]);
    att[e] = w;
    const int pos = atomicAdd(&cursor[d], 1);
    src_sorted[pos] = s;
    w_sorted[pos] = w;
}

// ---------------- supernode accumulation (sorted, no atomics) ----------------
__global__ __launch_bounds__(128) void k_supernode(const int* __restrict__ src_sorted,
                                                   const float* __restrict__ w_sorted,
                                                   const int* __restrict__ offs, const int* __restrict__ hist,
                                                   const float* __restrict__ nodes, float* __restrict__ out_sn) {
    const int c = blockIdx.x, t = threadIdx.x;
    const int base = offs[c], n = hist[c];
    __shared__ int ssm[256];
    __shared__ float swm[256];
    float a0 = 0.f, a1 = 0.f, a2 = 0.f, a3 = 0.f;
    for (int i0 = 0; i0 < n; i0 += 256) {
        const int m = min(256, n - i0);
        for (int i = t; i < m; i += 128) {
            ssm[i] = src_sorted[base + i0 + i];
            swm[i] = w_sorted[base + i0 + i];
        }
        __syncthreads();
        int i = 0;
        for (; i + 4 <= m; i += 4) {
            a0 = fmaf(swm[i + 0], nodes[(size_t)ssm[i + 0] * 128 + t], a0);
            a1 = fmaf(swm[i + 1], nodes[(size_t)ssm[i + 1] * 128 + t], a1);
            a2 = fmaf(swm[i + 2], nodes[(size_t)ssm[i + 2] * 128 + t], a2);
            a3 = fmaf(swm[i + 3], nodes[(size_t)ssm[i + 3] * 128 + t], a3);
        }
        for (; i < m; ++i) a0 = fmaf(swm[i], nodes[(size_t)ssm[i] * 128 + t], a0);
        __syncthreads();
    }
    out_sn[c * 128 + t] = ((a0 + a1) + (a2 + a3));
}

// ---------------- supergraph attention ----------------
__global__ __launch_bounds__(256) void k_sup_dot(const int* __restrict__ ss, const int* __restrict__ sd,
                                                 const float* __restrict__ means, float* __restrict__ satt,
                                                 unsigned* __restrict__ smax, unsigned* __restrict__ smin) {
    const int e = blockIdx.x * 256 + threadIdx.x;
    if (e >= ESN) return;
    const int s = ss[e], d = sd[e];
    const float4* av = (const float4*)(means + (size_t)s * 16);
    const float4* bv = (const float4*)(means + (size_t)d * 16);
    float dot = 0.f;
#pragma unroll
    for (int q = 0; q < 4; ++q) {
        const float4 a = av[q], b = bv[q];
        dot += a.x * b.x + a.y * b.y + a.z * b.z + a.w * b.w;
    }
    satt[e] = dot;
    const unsigned enc = fenc(dot);
    atomicMax(&smax[d], enc);
    atomicMin(&smin[d], enc);
}

__global__ __launch_bounds__(256) void k_sup_tanh(const int* __restrict__ sd, float* __restrict__ satt,
                                                  const unsigned* __restrict__ smax,
                                                  const unsigned* __restrict__ smin) {
    const int e = blockIdx.x * 256 + threadIdx.x;
    if (e >= ESN) return;
    const int d = sd[e];
    const float mx = fdec(smax[d]), mn = fdec(smin[d]);
    satt[e] = tanhf(2.f * (satt[e] - mn) / (EPSA + (mx - mn)));
}

// ---------------- superedge encoder (bf16 MFMA): [32 edges/block] ----------------
__global__ __launch_bounds__(256) void k_edge_mlp(
    const int* __restrict__ esv, const int* __restrict__ edv, const float* __restrict__ sn,
    const ushort_t* __restrict__ W1t, const float* __restrict__ b1, const float* __restrict__ g1,
    const float* __restrict__ be1, const ushort_t* __restrict__ W2t, const float* __restrict__ b2,
    const float* __restrict__ g2, const float* __restrict__ be2, float* __restrict__ out_se) {
    __shared__ ushort_t Xe[32 * 256];   // 16 KB, swizzled
    __shared__ ushort_t Hb[32 * 512];   // 32 KB, swizzled
    __shared__ float redS[4][32], redQ[4][32];
    const int tid = threadIdx.x;
    const int e0 = blockIdx.x * 32;

    // stage se_in = [sn[src] | sn[dst]] -> bf16 LDS
#pragma unroll
    for (int i = 0; i < 4; ++i) {
        const int c = tid + 256 * i;
        const int row = c >> 5, c8 = c & 31;
        const int node = (c8 < 16) ? esv[e0 + row] : edv[e0 + row];
        const float4* gp = (const float4*)(sn + (size_t)node * 128 + (c8 & 15) * 8);
        const float4 u = gp[0], v = gp[1];
        uint4 pk;
        pk.x = f2bf(u.x) | (f2bf(u.y) << 16);
        pk.y = f2bf(u.z) | (f2bf(u.w) << 16);
        pk.z = f2bf(v.x) | (f2bf(v.y) << 16);
        pk.w = f2bf(v.z) | (f2bf(v.w) << 16);
        const int byte = row * 512 + ((c8 * 16) ^ ((row & 7) << 4));
        *(uint4*)((char*)Xe + byte) = pk;
    }
    __syncthreads();

    const int wv = tid >> 6, l = tid & 63;
    const int q = l >> 4, c16 = l & 15;
    const int wcol0 = wv * 128;

    f32x4 acc[2][8];
#pragma unroll
    for (int mt = 0; mt < 2; ++mt)
#pragma unroll
        for (int nt = 0; nt < 8; ++nt) acc[mt][nt] = (f32x4){0.f, 0.f, 0.f, 0.f};

    // phase 1: H = X @ eW1  (M=32, N=128/wave, K=256)
#pragma unroll
    for (int ks = 0; ks < 8; ++ks) {
        bf16x8 af[2];
#pragma unroll
        for (int mt = 0; mt < 2; ++mt) {
            const int row = 16 * mt + c16;
            const int byte = row * 512 + ((64 * ks + 16 * q) ^ ((row & 7) << 4));
            af[mt] = __builtin_bit_cast(bf16x8, *(const uint4*)((const char*)Xe + byte));
        }
#pragma unroll
        for (int nt = 0; nt < 8; ++nt) {
            const int n = wcol0 + 16 * nt + c16;
            const bf16x8 bfr = __builtin_bit_cast(bf16x8, *(const uint4*)(W1t + n * 256 + 32 * ks + 8 * q));
#pragma unroll
            for (int mt = 0; mt < 2; ++mt)
                acc[mt][nt] = __builtin_amdgcn_mfma_f32_16x16x32_bf16(af[mt], bfr, acc[mt][nt], 0, 0, 0);
        }
    }

    // +b1, LN(512), ReLU -> Hb
    float b1v[8], g1v[8], bev[8];
#pragma unroll
    for (int nt = 0; nt < 8; ++nt) {
        const int col = wcol0 + 16 * nt + c16;
        b1v[nt] = b1[col]; g1v[nt] = g1[col]; bev[nt] = be1[col];
    }
    float sS[2][4], sQ[2][4];
#pragma unroll
    for (int mt = 0; mt < 2; ++mt)
#pragma unroll
        for (int r = 0; r < 4; ++r) {
            float s = 0.f, qq = 0.f;
#pragma unroll
            for (int nt = 0; nt < 8; ++nt) {
                const float h = acc[mt][nt][r] + b1v[nt];
                acc[mt][nt][r] = h;
                s += h; qq += h * h;
            }
#pragma unroll
            for (int off = 1; off < 16; off <<= 1) {
                s += __shfl_xor(s, off);
                qq += __shfl_xor(qq, off);
            }
            sS[mt][r] = s; sQ[mt][r] = qq;
        }
    if (c16 == 0) {
#pragma unroll
        for (int mt = 0; mt < 2; ++mt)
#pragma unroll
            for (int r = 0; r < 4; ++r) {
                const int row = 16 * mt + 4 * q + r;
                redS[wv][row] = sS[mt][r];
                redQ[wv][row] = sQ[mt][r];
            }
    }
    __syncthreads();
#pragma unroll
    for (int mt = 0; mt < 2; ++mt)
#pragma unroll
        for (int r = 0; r < 4; ++r) {
            const int row = 16 * mt + 4 * q + r;
            const float S = redS[0][row] + redS[1][row] + redS[2][row] + redS[3][row];
            const float Q = redQ[0][row] + redQ[1][row] + redQ[2][row] + redQ[3][row];
            const float m_ = S * (1.f / 512.f);
            const float iv = rsqrtf(Q * (1.f / 512.f) - m_ * m_ + 1e-5f);
#pragma unroll
            for (int nt = 0; nt < 8; ++nt) {
                const int col = wcol0 + 16 * nt + c16;
                const float rv = fmaxf((acc[mt][nt][r] - m_) * iv * g1v[nt] + bev[nt], 0.f);
                const int byte = row * 1024 + ((col * 2) ^ ((row & 7) << 4));
                *(ushort_t*)((char*)Hb + byte) = (ushort_t)f2bf(rv);
            }
        }
    __syncthreads();  // phase 2 reads all waves' Hb columns

    // phase 2: O = H' @ eW2  (M=32, N=32/wave, K=512)
    f32x4 acc2[2][2];
#pragma unroll
    for (int mt = 0; mt < 2; ++mt)
#pragma unroll
        for (int nt = 0; nt < 2; ++nt) acc2[mt][nt] = (f32x4){0.f, 0.f, 0.f, 0.f};
#pragma unroll 4
    for (int ks = 0; ks < 16; ++ks) {
        bf16x8 bfb[2];
#pragma unroll
        for (int nt = 0; nt < 2; ++nt) {
            const int n = wv * 32 + 16 * nt + c16;
            bfb[nt] = __builtin_bit_cast(bf16x8, *(const uint4*)(W2t + n * 512 + 32 * ks + 8 * q));
        }
#pragma unroll
        for (int mt = 0; mt < 2; ++mt) {
            const int row = 16 * mt + c16;
            const int byte = row * 1024 + ((64 * ks + 16 * q) ^ ((row & 7) << 4));
            const bf16x8 ha = __builtin_bit_cast(bf16x8, *(const uint4*)((const char*)Hb + byte));
#pragma unroll
            for (int nt = 0; nt < 2; ++nt)
                acc2[mt][nt] = __builtin_amdgcn_mfma_f32_16x16x32_bf16(ha, bfb[nt], acc2[mt][nt], 0, 0, 0);
        }
    }

    // +b2, LN(128), ReLU, store
    float b2v[2], g2v[2], be2v[2];
#pragma unroll
    for (int nt = 0; nt < 2; ++nt) {
        const int col = wv * 32 + 16 * nt + c16;
        b2v[nt] = b2[col]; g2v[nt] = g2[col]; be2v[nt] = be2[col];
    }
    float sS2[2][4], sQ2[2][4];
#pragma unroll
    for (int mt = 0; mt < 2; ++mt)
#pragma unroll
        for (int r = 0; r < 4; ++r) {
            float s = 0.f, qq = 0.f;
#pragma unroll
            for (int nt = 0; nt < 2; ++nt) {
                const float h = acc2[mt][nt][r] + b2v[nt];
                acc2[mt][nt][r] = h;
                s += h; qq += h * h;
            }
#pragma unroll
            for (int off = 1; off < 16; off <<= 1) {
                s += __shfl_xor(s, off);
                qq += __shfl_xor(qq, off);
            }
            sS2[mt][r] = s; sQ2[mt][r] = qq;
        }
    __syncthreads();  // safe reuse of redS/redQ
    if (c16 == 0) {
#pragma unroll
        for (int mt = 0; mt < 2; ++mt)
#pragma unroll
            for (int r = 0; r < 4; ++r) {
                const int row = 16 * mt + 4 * q + r;
                redS[wv][row] = sS2[mt][r];
                redQ[wv][row] = sQ2[mt][r];
            }
    }
    __syncthreads();
#pragma unroll
    for (int mt = 0; mt < 2; ++mt)
#pragma unroll
        for (int r = 0; r < 4; ++r) {
            const int row = 16 * mt + 4 * q + r;
            const float S = redS[0][row] + redS[1][row] + redS[2][row] + redS[3][row];
            const float Q = redQ[0][row] + redQ[1][row] + redQ[2][row] + redQ[3][row];
            const float m_ = S * (1.f / 128.f);
            const float iv = rsqrtf(Q * (1.f / 128.f) - m_ * m_ + 1e-5f);
#pragma unroll
            for (int nt = 0; nt < 2; ++nt) {
                const int col = wv * 32 + 16 * nt + c16;
                const float o = fmaxf((acc2[mt][nt][r] - m_) * iv * g2v[nt] + be2v[nt], 0.f);
                out_se[(size_t)(e0 + row) * 128 + col] = o;
            }
        }
}

extern "C" void kernel_launch(void* const* d_in, const int* in_sizes, int n_in,
                              void* d_out, int out_size, void* d_ws, size_t ws_size,
                              hipStream_t stream) {
    const float* nodes = (const float*)d_in[0];
    const int* clusters = (const int*)d_in[1];
    const int* bsrc = (const int*)d_in[2];
    const int* bdst = (const int*)d_in[3];
    const int* susrc = (const int*)d_in[4];
    const int* sudst = (const int*)d_in[5];
    const float* cW1 = (const float*)d_in[6];
    const float* cb1 = (const float*)d_in[7];
    const float* cg1 = (const float*)d_in[8];
    const float* cbe1 = (const float*)d_in[9];
    const float* cW2 = (const float*)d_in[10];
    const float* cb2 = (const float*)d_in[11];
    const float* eW1 = (const float*)d_in[12];
    const float* eb1 = (const float*)d_in[13];
    const float* eg1 = (const float*)d_in[14];
    const float* ebe1 = (const float*)d_in[15];
    const float* eW2 = (const float*)d_in[16];
    const float* eb2 = (const float*)d_in[17];
    const float* eg2 = (const float*)d_in[18];
    const float* ebe2 = (const float*)d_in[19];

    float* out_sn = (float*)d_out;
    float* out_se = out_sn + (size_t)CC * 128;
    float* out_bip = out_se + (size_t)ESN * 128;
    float* out_satt = out_bip + EBN;

    // workspace layout (u32 units)
    float* sums = (float*)d_ws;                            // 32000
    float* cnt = sums + 32000;                             // 2000
    int* hist = (int*)(cnt + 2000);                        // 2000
    unsigned* smax = (unsigned*)(hist + 2000);             // 2000
    float* asum = (float*)(smax + 2000);                   // 200000
    unsigned* amax = (unsigned*)(asum + 200000);           // 200000
    unsigned* amin = amax + 200000;                        // 200000
    unsigned* smin = amin + 200000;                        // 2000
    float* emb = (float*)(smin + 2000);                    // 3200000
    float* means = emb + 3200000;                          // 32000
    int* offs = (int*)(means + 32000);                     // 2000
    int* cursor = offs + 2000;                             // 2000
    int* src_sorted = cursor + 2000;                       // 2000000
    float* w_sorted = (float*)(src_sorted + 2000000);      // 2000000
    ushort_t* cW1hi = (ushort_t*)(w_sorted + 2000000);     // 65536 bf16
    ushort_t* cW1lo = cW1hi + 512 * 128;                   // 65536
    ushort_t* eW1t = cW1lo + 512 * 128;                    // 131072
    ushort_t* eW2t = eW1t + 512 * 256;                     // 65536

    // init: [sums|cnt|hist|smax|asum|amax] = 0 ; [amin|smin] = 0xFF
    hipMemsetAsync(sums, 0, (size_t)(32000 + 2000 + 2000 + 2000 + 200000 + 200000) * 4, stream);
    hipMemsetAsync(amin, 0xFF, (size_t)(200000 + 2000) * 4, stream);

    k_conv<<<1024, 256, 0, stream>>>(cW1, eW1, eW2, cW1hi, cW1lo, eW1t, eW2t);
    k_hist<<<256, 256, 0, stream>>>(bdst, hist);
    k_scan<<<1, 1024, 0, stream>>>(hist, offs, cursor);
    k_mlp1<<<NN / 32, 256, 0, stream>>>(nodes, clusters, cW1hi, cW1lo, cb1, cg1, cbe1, cW2, cb2, emb, sums, cnt);
    k_means<<<(CC * 16) / 256, 256, 0, stream>>>(sums, cnt, means);
    k_bip_dot<<<(EBN + 255) / 256, 256, 0, stream>>>(bsrc, bdst, emb, means, out_bip, amax, amin);
    k_bip_exp<<<(EBN + 255) / 256, 256, 0, stream>>>(bsrc, out_bip, amax, amin, asum);
    k_bip_scatter<<<(EBN + 255) / 256, 256, 0, stream>>>(bsrc, bdst, out_bip, asum, cursor, src_sorted, w_sorted);
    k_supernode<<<CC, 128, 0, stream>>>(src_sorted, w_sorted, offs, hist, nodes, out_sn);
    k_sup_dot<<<(ESN + 255) / 256, 256, 0, stream>>>(susrc, sudst, means, out_satt, smax, smin);
    k_sup_tanh<<<(ESN + 255) / 256, 256, 0, stream>>>(sudst, out_satt, smax, smin);
    k_edge_mlp<<<ESN / 32, 256, 0, stream>>>(susrc, sudst, out_sn, eW1t, eb1, eg1, ebe1, eW2t, eb2, eg2, ebe2, out_se);
}

// Round 4
// 1052.564 us; speedup vs baseline: 1.5591x; 1.2238x over previous
//
#include <hip/hip_runtime.h>

#define NN 200000
#define CC 2000
#define EBN 2000000
#define ESN 40000
#define EPSA 1e-4f

typedef unsigned short ushort_t;
typedef float f32x4 __attribute__((ext_vector_type(4)));
typedef __bf16 bf16x8 __attribute__((ext_vector_type(8)));

__device__ __forceinline__ unsigned fenc(float f) {
    unsigned b = __float_as_uint(f);
    return (b & 0x80000000u) ? ~b : (b | 0x80000000u);
}
__device__ __forceinline__ float fdec(unsigned u) {
    return (u & 0x80000000u) ? __uint_as_float(u ^ 0x80000000u) : __uint_as_float(~u);
}
__device__ __forceinline__ unsigned f2bf(float f) {  // RNE f32 -> bf16 bits
    unsigned u = __float_as_uint(f);
    return (u + 0x7fffu + ((u >> 16) & 1u)) >> 16;
}
__device__ __forceinline__ void split2(float f, unsigned& hi, unsigned& lo) {
    hi = f2bf(f);
    const float fh = __uint_as_float(hi << 16);
    lo = f2bf(f - fh);
}

// ---- weight convert: cW1 -> hi/lo bf16 [N][K]; cW2 -> hi/lo [16][512]; eW1,eW2 -> bf16 [N][K] ----
__global__ __launch_bounds__(256) void k_conv(const float* __restrict__ cW1, const float* __restrict__ cW2,
                                              const float* __restrict__ eW1, const float* __restrict__ eW2,
                                              ushort_t* __restrict__ cW1hi, ushort_t* __restrict__ cW1lo,
                                              ushort_t* __restrict__ cW2hi, ushort_t* __restrict__ cW2lo,
                                              ushort_t* __restrict__ eW1t, ushort_t* __restrict__ eW2t) {
    int id = blockIdx.x * 256 + threadIdx.x;
    if (id < 65536) {
        const int n = id >> 7, k = id & 127;
        unsigned hi, lo;
        split2(cW1[k * 512 + n], hi, lo);
        cW1hi[id] = (ushort_t)hi;
        cW1lo[id] = (ushort_t)lo;
        return;
    }
    id -= 65536;
    if (id < 8192) {
        const int n = id >> 9, k = id & 511;
        unsigned hi, lo;
        split2(cW2[k * 16 + n], hi, lo);
        cW2hi[id] = (ushort_t)hi;
        cW2lo[id] = (ushort_t)lo;
        return;
    }
    id -= 8192;
    if (id < 131072) { const int n = id >> 8, k = id & 255; eW1t[id] = (ushort_t)f2bf(eW1[k * 512 + n]); return; }
    id -= 131072;
    if (id < 65536) { const int n = id >> 9, k = id & 511; eW2t[id] = (ushort_t)f2bf(eW2[k * 128 + n]); return; }
}

// ---------------- histogram of bip_dst ----------------
__global__ __launch_bounds__(256) void k_hist(const int* __restrict__ bdst, int* __restrict__ hist) {
    __shared__ int h[CC];
    const int t = threadIdx.x;
    for (int i = t; i < CC; i += 256) h[i] = 0;
    __syncthreads();
    for (int e = blockIdx.x * 256 + t; e < EBN; e += gridDim.x * 256)
        atomicAdd(&h[bdst[e]], 1);
    __syncthreads();
    for (int i = t; i < CC; i += 256) if (h[i]) atomicAdd(&hist[i], h[i]);
}

// ---------------- exclusive scan over C=2000 ----------------
__global__ __launch_bounds__(1024) void k_scan(const int* __restrict__ hist, int* __restrict__ offs,
                                               int* __restrict__ cursor) {
    __shared__ int buf[2][2048];
    const int t = threadIdx.x;
    buf[0][t]        = (t        < CC) ? hist[t]        : 0;
    buf[0][t + 1024] = (t + 1024 < CC) ? hist[t + 1024] : 0;
    __syncthreads();
    int pp = 0;
    for (int off = 1; off < 2048; off <<= 1) {
        const int np = pp ^ 1;
        for (int i = t; i < 2048; i += 1024) {
            int v = buf[pp][i];
            if (i >= off) v += buf[pp][i - off];
            buf[np][i] = v;
        }
        pp = np;
        __syncthreads();
    }
    for (int i = t; i < CC; i += 1024) {
        const int ex = (i == 0) ? 0 : buf[pp][i - 1];
        offs[i] = ex;
        cursor[i] = ex;
    }
}

// ---------------- node MLP: split-bf16 MFMA both phases ----------------
// 32 rows/block, 4 waves; wave w owns hidden cols [128w,128w+128)
__global__ __launch_bounds__(256) void k_mlp1(
    const float* __restrict__ nodes, const int* __restrict__ clusters,
    const ushort_t* __restrict__ W1hi, const ushort_t* __restrict__ W1lo, const float* __restrict__ b1,
    const float* __restrict__ g1, const float* __restrict__ be1,
    const ushort_t* __restrict__ W2hi, const ushort_t* __restrict__ W2lo, const float* __restrict__ b2,
    float* __restrict__ emb, float* __restrict__ sums, float* __restrict__ cnt) {
    __shared__ char Ubuf[65536];              // union: X (16 KB) then H hi/lo (64 KB)
    __shared__ float redS[4][32], redQ[4][32];
    __shared__ float Cbuf[4][32][16];
    ushort_t* Xhi = (ushort_t*)Ubuf;          // 8 KB, XOR-swizzled
    ushort_t* Xlo = (ushort_t*)(Ubuf + 8192); // 8 KB
    char* Hhi = Ubuf;                         // 32 KB  [32][512] bf16, swizzled
    char* Hlo = Ubuf + 32768;                 // 32 KB
    const int tid = threadIdx.x;
    const int row0 = blockIdx.x * 32;

    // stage X -> (hi,lo) bf16 LDS (swizzled)
#pragma unroll
    for (int i = 0; i < 2; ++i) {
        const int c = tid + 256 * i;
        const int row = c >> 4, c8 = c & 15;
        const float4* gp = (const float4*)(nodes + (size_t)(row0 + row) * 128 + c8 * 8);
        const float4 u = gp[0], v = gp[1];
        unsigned h0, l0, h1, l1, h2, l2, h3, l3, h4, l4, h5, l5, h6, l6, h7, l7;
        split2(u.x, h0, l0); split2(u.y, h1, l1); split2(u.z, h2, l2); split2(u.w, h3, l3);
        split2(v.x, h4, l4); split2(v.y, h5, l5); split2(v.z, h6, l6); split2(v.w, h7, l7);
        uint4 pkh, pkl;
        pkh.x = h0 | (h1 << 16); pkh.y = h2 | (h3 << 16); pkh.z = h4 | (h5 << 16); pkh.w = h6 | (h7 << 16);
        pkl.x = l0 | (l1 << 16); pkl.y = l2 | (l3 << 16); pkl.z = l4 | (l5 << 16); pkl.w = l6 | (l7 << 16);
        const int byte = row * 256 + ((c8 * 16) ^ ((row & 7) << 4));
        *(uint4*)((char*)Xhi + byte) = pkh;
        *(uint4*)((char*)Xlo + byte) = pkl;
    }
    __syncthreads();

    const int wv = tid >> 6, l = tid & 63;
    const int q = l >> 4, c16 = l & 15;
    const int wcol0 = wv * 128;

    f32x4 acc[2][8];
#pragma unroll
    for (int mt = 0; mt < 2; ++mt)
#pragma unroll
        for (int nt = 0; nt < 8; ++nt) acc[mt][nt] = (f32x4){0.f, 0.f, 0.f, 0.f};

    // phase 1: H = X @ W1 with 3-term split (error ~2^-17)
#pragma unroll
    for (int ks = 0; ks < 4; ++ks) {
        bf16x8 ah[2], al[2];
#pragma unroll
        for (int mt = 0; mt < 2; ++mt) {
            const int row = 16 * mt + c16;
            const int byte = row * 256 + ((64 * ks + 16 * q) ^ ((row & 7) << 4));
            ah[mt] = __builtin_bit_cast(bf16x8, *(const uint4*)((const char*)Xhi + byte));
            al[mt] = __builtin_bit_cast(bf16x8, *(const uint4*)((const char*)Xlo + byte));
        }
#pragma unroll
        for (int nt = 0; nt < 8; ++nt) {
            const int n = wcol0 + 16 * nt + c16;
            const bf16x8 bhi = __builtin_bit_cast(bf16x8, *(const uint4*)(W1hi + n * 128 + 32 * ks + 8 * q));
            const bf16x8 blo = __builtin_bit_cast(bf16x8, *(const uint4*)(W1lo + n * 128 + 32 * ks + 8 * q));
#pragma unroll
            for (int mt = 0; mt < 2; ++mt) {
                acc[mt][nt] = __builtin_amdgcn_mfma_f32_16x16x32_bf16(ah[mt], bhi, acc[mt][nt], 0, 0, 0);
                acc[mt][nt] = __builtin_amdgcn_mfma_f32_16x16x32_bf16(al[mt], bhi, acc[mt][nt], 0, 0, 0);
                acc[mt][nt] = __builtin_amdgcn_mfma_f32_16x16x32_bf16(ah[mt], blo, acc[mt][nt], 0, 0, 0);
            }
        }
    }

    // phase 1.5: +b1, LN(512) partials
    float b1v[8], g1v[8], bev[8];
#pragma unroll
    for (int nt = 0; nt < 8; ++nt) {
        const int col = wcol0 + 16 * nt + c16;
        b1v[nt] = b1[col]; g1v[nt] = g1[col]; bev[nt] = be1[col];
    }
    float sS[2][4], sQ[2][4];
#pragma unroll
    for (int mt = 0; mt < 2; ++mt)
#pragma unroll
        for (int r = 0; r < 4; ++r) {
            float s = 0.f, qq = 0.f;
#pragma unroll
            for (int nt = 0; nt < 8; ++nt) {
                const float h = acc[mt][nt][r] + b1v[nt];
                acc[mt][nt][r] = h;
                s += h; qq += h * h;
            }
#pragma unroll
            for (int off = 1; off < 16; off <<= 1) {
                s += __shfl_xor(s, off);
                qq += __shfl_xor(qq, off);
            }
            sS[mt][r] = s; sQ[mt][r] = qq;
        }
    if (c16 == 0) {
#pragma unroll
        for (int mt = 0; mt < 2; ++mt)
#pragma unroll
            for (int r = 0; r < 4; ++r) {
                const int row = 16 * mt + 4 * q + r;
                redS[wv][row] = sS[mt][r];
                redQ[wv][row] = sQ[mt][r];
            }
    }
    __syncthreads();  // after this barrier X is dead (all waves finished phase 1)

    // apply LN+ReLU (fp32), split to hi/lo, store own 32x128 K-slice into H LDS
#pragma unroll
    for (int mt = 0; mt < 2; ++mt)
#pragma unroll
        for (int r = 0; r < 4; ++r) {
            const int row = 16 * mt + 4 * q + r;
            const float S = redS[0][row] + redS[1][row] + redS[2][row] + redS[3][row];
            const float Q = redQ[0][row] + redQ[1][row] + redQ[2][row] + redQ[3][row];
            const float m_ = S * (1.f / 512.f);
            const float iv = rsqrtf(Q * (1.f / 512.f) - m_ * m_ + 1e-5f);
            const int swz = (row & 7) << 4;
            const int rb = row * 1024;
#pragma unroll
            for (int nt = 0; nt < 8; ++nt) {
                const float rv = fmaxf((acc[mt][nt][r] - m_) * iv * g1v[nt] + bev[nt], 0.f);
                unsigned hi, lo;
                split2(rv, hi, lo);
                const int col = wcol0 + 16 * nt + c16;
                const int byte = rb + ((col * 2) ^ swz);
                *(ushort_t*)(Hhi + byte) = (ushort_t)hi;
                *(ushort_t*)(Hlo + byte) = (ushort_t)lo;
            }
        }

    // phase 2: partial emb = H' @ W2 over this wave's K-slice, 3-term split MFMA.
    // No barrier: each wave reads exactly the H region it wrote.
    f32x4 acc2[2];
    acc2[0] = (f32x4){0.f, 0.f, 0.f, 0.f};
    acc2[1] = (f32x4){0.f, 0.f, 0.f, 0.f};
#pragma unroll
    for (int ks = 0; ks < 4; ++ks) {
        const int k = wcol0 + 32 * ks + 8 * q;
        const bf16x8 bhi = __builtin_bit_cast(bf16x8, *(const uint4*)(W2hi + c16 * 512 + k));
        const bf16x8 blo = __builtin_bit_cast(bf16x8, *(const uint4*)(W2lo + c16 * 512 + k));
#pragma unroll
        for (int mt = 0; mt < 2; ++mt) {
            const int row = 16 * mt + c16;
            const int byte = row * 1024 + ((k * 2) ^ ((row & 7) << 4));
            const bf16x8 ah = __builtin_bit_cast(bf16x8, *(const uint4*)(Hhi + byte));
            const bf16x8 al = __builtin_bit_cast(bf16x8, *(const uint4*)(Hlo + byte));
            acc2[mt] = __builtin_amdgcn_mfma_f32_16x16x32_bf16(ah, bhi, acc2[mt], 0, 0, 0);
            acc2[mt] = __builtin_amdgcn_mfma_f32_16x16x32_bf16(al, bhi, acc2[mt], 0, 0, 0);
            acc2[mt] = __builtin_amdgcn_mfma_f32_16x16x32_bf16(ah, blo, acc2[mt], 0, 0, 0);
        }
    }
#pragma unroll
    for (int mt = 0; mt < 2; ++mt)
#pragma unroll
        for (int r = 0; r < 4; ++r) Cbuf[wv][16 * mt + 4 * q + r][c16] = acc2[mt][r];
    __syncthreads();

    // final: cross-wave K-reduce, +b2, l2norm, store + cluster atomics
#pragma unroll
    for (int rep = 0; rep < 2; ++rep) {
        const int slot = tid + 256 * rep;
        const int row = slot >> 4, col = slot & 15;
        float val = Cbuf[0][row][col] + Cbuf[1][row][col] + Cbuf[2][row][col] + Cbuf[3][row][col] + b2[col];
        float ss = val * val;
#pragma unroll
        for (int off = 1; off < 16; off <<= 1) ss += __shfl_xor(ss, off);
        const float ev = val / fmaxf(sqrtf(ss), 1e-12f);
        const int grow = row0 + row;
        emb[(size_t)grow * 16 + col] = ev;
        const int cl = clusters[grow];
        if (cl >= 0) {
            atomicAdd(&sums[cl * 16 + col], ev);
            if (col == 0) atomicAdd(&cnt[cl], 1.f);
        }
    }
}

// ---------------- cluster means + l2norm ----------------
__global__ __launch_bounds__(256) void k_means(const float* __restrict__ sums, const float* __restrict__ cnt,
                                               float* __restrict__ means) {
    const int t = blockIdx.x * 256 + threadIdx.x;
    const int c = t >> 4;
    const float v = sums[t] / fmaxf(cnt[c], 1.f);
    float sq = v * v;
#pragma unroll
    for (int off = 1; off < 16; off <<= 1) sq += __shfl_xor(sq, off, 16);
    means[t] = v / fmaxf(sqrtf(sq), 1e-12f);
}

// ---------------- bipartite attention pass A: dots + seg max/min ----------------
__global__ __launch_bounds__(256) void k_bip_dot(const int* __restrict__ src, const int* __restrict__ dst,
                                                 const float* __restrict__ emb, const float* __restrict__ means,
                                                 float* __restrict__ att, unsigned* __restrict__ amax,
                                                 unsigned* __restrict__ amin) {
    const int e = blockIdx.x * 256 + threadIdx.x;
    if (e >= EBN) return;
    const int s = src[e], d = dst[e];
    const float4* ev = (const float4*)(emb + (size_t)s * 16);
    const float4* mv = (const float4*)(means + (size_t)d * 16);
    float dot = 0.f;
#pragma unroll
    for (int q = 0; q < 4; ++q) {
        const float4 a = ev[q], b = mv[q];
        dot += a.x * b.x + a.y * b.y + a.z * b.z + a.w * b.w;
    }
    att[e] = dot;
    const unsigned enc = fenc(dot);
    atomicMax(&amax[s], enc);
    atomicMin(&amin[s], enc);
}

// ---------------- pass B: exp + seg sum ----------------
__global__ __launch_bounds__(256) void k_bip_exp(const int* __restrict__ src, float* __restrict__ att,
                                                 const unsigned* __restrict__ amax,
                                                 const unsigned* __restrict__ amin, float* __restrict__ asum) {
    const int e = blockIdx.x * 256 + threadIdx.x;
    if (e >= EBN) return;
    const int s = src[e];
    const float mx = fdec(amax[s]), mn = fdec(amin[s]);
    const float a = expf(2.f * (att[e] - mn) / (EPSA + (mx - mn)));
    att[e] = a;
    atomicAdd(&asum[s], a);
}

// ---------------- pass C: normalize + counting-sort scatter ----------------
__global__ __launch_bounds__(256) void k_bip_scatter(const int* __restrict__ src, const int* __restrict__ dst,
                                                     float* __restrict__ att, const float* __restrict__ asum,
                                                     int* __restrict__ cursor, int* __restrict__ src_sorted,
                                                     float* __restrict__ w_sorted) {
    const int e = blockIdx.x * 256 + threadIdx.x;
    if (e >= EBN) return;
    const int s = src[e], d = dst[e];
    const float w = att[e] / (EPSA + asum[s]);
    att[e] = w;
    const int pos = atomicAdd(&cursor[d], 1);
    src_sorted[pos] = s;
    w_sorted[pos] = w;
}

// ---------------- supernode accumulation (sorted, no atomics) ----------------
__global__ __launch_bounds__(128) void k_supernode(const int* __restrict__ src_sorted,
                                                   const float* __restrict__ w_sorted,
                                                   const int* __restrict__ offs, const int* __restrict__ hist,
                                                   const float* __restrict__ nodes, float* __restrict__ out_sn) {
    const int c = blockIdx.x, t = threadIdx.x;
    const int base = offs[c], n = hist[c];
    __shared__ int ssm[256];
    __shared__ float swm[256];
    float a0 = 0.f, a1 = 0.f, a2 = 0.f, a3 = 0.f;
    for (int i0 = 0; i0 < n; i0 += 256) {
        const int m = min(256, n - i0);
        for (int i = t; i < m; i += 128) {
            ssm[i] = src_sorted[base + i0 + i];
            swm[i] = w_sorted[base + i0 + i];
        }
        __syncthreads();
        int i = 0;
        for (; i + 4 <= m; i += 4) {
            a0 = fmaf(swm[i + 0], nodes[(size_t)ssm[i + 0] * 128 + t], a0);
            a1 = fmaf(swm[i + 1], nodes[(size_t)ssm[i + 1] * 128 + t], a1);
            a2 = fmaf(swm[i + 2], nodes[(size_t)ssm[i + 2] * 128 + t], a2);
            a3 = fmaf(swm[i + 3], nodes[(size_t)ssm[i + 3] * 128 + t], a3);
        }
        for (; i < m; ++i) a0 = fmaf(swm[i], nodes[(size_t)ssm[i] * 128 + t], a0);
        __syncthreads();
    }
    out_sn[c * 128 + t] = ((a0 + a1) + (a2 + a3));
}

// ---------------- supergraph attention ----------------
__global__ __launch_bounds__(256) void k_sup_dot(const int* __restrict__ ss, const int* __restrict__ sd,
                                                 const float* __restrict__ means, float* __restrict__ satt,
                                                 unsigned* __restrict__ smax, unsigned* __restrict__ smin) {
    const int e = blockIdx.x * 256 + threadIdx.x;
    if (e >= ESN) return;
    const int s = ss[e], d = sd[e];
    const float4* av = (const float4*)(means + (size_t)s * 16);
    const float4* bv = (const float4*)(means + (size_t)d * 16);
    float dot = 0.f;
#pragma unroll
    for (int q = 0; q < 4; ++q) {
        const float4 a = av[q], b = bv[q];
        dot += a.x * b.x + a.y * b.y + a.z * b.z + a.w * b.w;
    }
    satt[e] = dot;
    const unsigned enc = fenc(dot);
    atomicMax(&smax[d], enc);
    atomicMin(&smin[d], enc);
}

__global__ __launch_bounds__(256) void k_sup_tanh(const int* __restrict__ sd, float* __restrict__ satt,
                                                  const unsigned* __restrict__ smax,
                                                  const unsigned* __restrict__ smin) {
    const int e = blockIdx.x * 256 + threadIdx.x;
    if (e >= ESN) return;
    const int d = sd[e];
    const float mx = fdec(smax[d]), mn = fdec(smin[d]);
    satt[e] = tanhf(2.f * (satt[e] - mn) / (EPSA + (mx - mn)));
}

// ---------------- superedge encoder (bf16 MFMA): [32 edges/block] ----------------
__global__ __launch_bounds__(256) void k_edge_mlp(
    const int* __restrict__ esv, const int* __restrict__ edv, const float* __restrict__ sn,
    const ushort_t* __restrict__ W1t, const float* __restrict__ b1, const float* __restrict__ g1,
    const float* __restrict__ be1, const ushort_t* __restrict__ W2t, const float* __restrict__ b2,
    const float* __restrict__ g2, const float* __restrict__ be2, float* __restrict__ out_se) {
    __shared__ ushort_t Xe[32 * 256];   // 16 KB, swizzled
    __shared__ ushort_t Hb[32 * 512];   // 32 KB, swizzled
    __shared__ float redS[4][32], redQ[4][32];
    const int tid = threadIdx.x;
    const int e0 = blockIdx.x * 32;

    // stage se_in = [sn[src] | sn[dst]] -> bf16 LDS
#pragma unroll
    for (int i = 0; i < 4; ++i) {
        const int c = tid + 256 * i;
        const int row = c >> 5, c8 = c & 31;
        const int node = (c8 < 16) ? esv[e0 + row] : edv[e0 + row];
        const float4* gp = (const float4*)(sn + (size_t)node * 128 + (c8 & 15) * 8);
        const float4 u = gp[0], v = gp[1];
        uint4 pk;
        pk.x = f2bf(u.x) | (f2bf(u.y) << 16);
        pk.y = f2bf(u.z) | (f2bf(u.w) << 16);
        pk.z = f2bf(v.x) | (f2bf(v.y) << 16);
        pk.w = f2bf(v.z) | (f2bf(v.w) << 16);
        const int byte = row * 512 + ((c8 * 16) ^ ((row & 7) << 4));
        *(uint4*)((char*)Xe + byte) = pk;
    }
    __syncthreads();

    const int wv = tid >> 6, l = tid & 63;
    const int q = l >> 4, c16 = l & 15;
    const int wcol0 = wv * 128;

    f32x4 acc[2][8];
#pragma unroll
    for (int mt = 0; mt < 2; ++mt)
#pragma unroll
        for (int nt = 0; nt < 8; ++nt) acc[mt][nt] = (f32x4){0.f, 0.f, 0.f, 0.f};

    // phase 1: H = X @ eW1  (M=32, N=128/wave, K=256)
#pragma unroll
    for (int ks = 0; ks < 8; ++ks) {
        bf16x8 af[2];
#pragma unroll
        for (int mt = 0; mt < 2; ++mt) {
            const int row = 16 * mt + c16;
            const int byte = row * 512 + ((64 * ks + 16 * q) ^ ((row & 7) << 4));
            af[mt] = __builtin_bit_cast(bf16x8, *(const uint4*)((const char*)Xe + byte));
        }
#pragma unroll
        for (int nt = 0; nt < 8; ++nt) {
            const int n = wcol0 + 16 * nt + c16;
            const bf16x8 bfr = __builtin_bit_cast(bf16x8, *(const uint4*)(W1t + n * 256 + 32 * ks + 8 * q));
#pragma unroll
            for (int mt = 0; mt < 2; ++mt)
                acc[mt][nt] = __builtin_amdgcn_mfma_f32_16x16x32_bf16(af[mt], bfr, acc[mt][nt], 0, 0, 0);
        }
    }

    // +b1, LN(512), ReLU -> Hb
    float b1v[8], g1v[8], bev[8];
#pragma unroll
    for (int nt = 0; nt < 8; ++nt) {
        const int col = wcol0 + 16 * nt + c16;
        b1v[nt] = b1[col]; g1v[nt] = g1[col]; bev[nt] = be1[col];
    }
    float sS[2][4], sQ[2][4];
#pragma unroll
    for (int mt = 0; mt < 2; ++mt)
#pragma unroll
        for (int r = 0; r < 4; ++r) {
            float s = 0.f, qq = 0.f;
#pragma unroll
            for (int nt = 0; nt < 8; ++nt) {
                const float h = acc[mt][nt][r] + b1v[nt];
                acc[mt][nt][r] = h;
                s += h; qq += h * h;
            }
#pragma unroll
            for (int off = 1; off < 16; off <<= 1) {
                s += __shfl_xor(s, off);
                qq += __shfl_xor(qq, off);
            }
            sS[mt][r] = s; sQ[mt][r] = qq;
        }
    if (c16 == 0) {
#pragma unroll
        for (int mt = 0; mt < 2; ++mt)
#pragma unroll
            for (int r = 0; r < 4; ++r) {
                const int row = 16 * mt + 4 * q + r;
                redS[wv][row] = sS[mt][r];
                redQ[wv][row] = sQ[mt][r];
            }
    }
    __syncthreads();
#pragma unroll
    for (int mt = 0; mt < 2; ++mt)
#pragma unroll
        for (int r = 0; r < 4; ++r) {
            const int row = 16 * mt + 4 * q + r;
            const float S = redS[0][row] + redS[1][row] + redS[2][row] + redS[3][row];
            const float Q = redQ[0][row] + redQ[1][row] + redQ[2][row] + redQ[3][row];
            const float m_ = S * (1.f / 512.f);
            const float iv = rsqrtf(Q * (1.f / 512.f) - m_ * m_ + 1e-5f);
#pragma unroll
            for (int nt = 0; nt < 8; ++nt) {
                const int col = wcol0 + 16 * nt + c16;
                const float rv = fmaxf((acc[mt][nt][r] - m_) * iv * g1v[nt] + bev[nt], 0.f);
                const int byte = row * 1024 + ((col * 2) ^ ((row & 7) << 4));
                *(ushort_t*)((char*)Hb + byte) = (ushort_t)f2bf(rv);
            }
        }
    __syncthreads();  // phase 2 reads all waves' Hb columns

    // phase 2: O = H' @ eW2  (M=32, N=32/wave, K=512)
    f32x4 acc2[2][2];
#pragma unroll
    for (int mt = 0; mt < 2; ++mt)
#pragma unroll
        for (int nt = 0; nt < 2; ++nt) acc2[mt][nt] = (f32x4){0.f, 0.f, 0.f, 0.f};
#pragma unroll 4
    for (int ks = 0; ks < 16; ++ks) {
        bf16x8 bfb[2];
#pragma unroll
        for (int nt = 0; nt < 2; ++nt) {
            const int n = wv * 32 + 16 * nt + c16;
            bfb[nt] = __builtin_bit_cast(bf16x8, *(const uint4*)(W2t + n * 512 + 32 * ks + 8 * q));
        }
#pragma unroll
        for (int mt = 0; mt < 2; ++mt) {
            const int row = 16 * mt + c16;
            const int byte = row * 1024 + ((64 * ks + 16 * q) ^ ((row & 7) << 4));
            const bf16x8 ha = __builtin_bit_cast(bf16x8, *(const uint4*)((const char*)Hb + byte));
#pragma unroll
            for (int nt = 0; nt < 2; ++nt)
                acc2[mt][nt] = __builtin_amdgcn_mfma_f32_16x16x32_bf16(ha, bfb[nt], acc2[mt][nt], 0, 0, 0);
        }
    }

    // +b2, LN(128), ReLU, store
    float b2v[2], g2v[2], be2v[2];
#pragma unroll
    for (int nt = 0; nt < 2; ++nt) {
        const int col = wv * 32 + 16 * nt + c16;
        b2v[nt] = b2[col]; g2v[nt] = g2[col]; be2v[nt] = be2[col];
    }
    float sS2[2][4], sQ2[2][4];
#pragma unroll
    for (int mt = 0; mt < 2; ++mt)
#pragma unroll
        for (int r = 0; r < 4; ++r) {
            float s = 0.f, qq = 0.f;
#pragma unroll
            for (int nt = 0; nt < 2; ++nt) {
                const float h = acc2[mt][nt][r] + b2v[nt];
                acc2[mt][nt][r] = h;
                s += h; qq += h * h;
            }
#pragma unroll
            for (int off = 1; off < 16; off <<= 1) {
                s += __shfl_xor(s, off);
                qq += __shfl_xor(qq, off);
            }
            sS2[mt][r] = s; sQ2[mt][r] = qq;
        }
    __syncthreads();  // safe reuse of redS/redQ
    if (c16 == 0) {
#pragma unroll
        for (int mt = 0; mt < 2; ++mt)
#pragma unroll
            for (int r = 0; r < 4; ++r) {
                const int row = 16 * mt + 4 * q + r;
                redS[wv][row] = sS2[mt][r];
                redQ[wv][row] = sQ2[mt][r];
            }
    }
    __syncthreads();
#pragma unroll
    for (int mt = 0; mt < 2; ++mt)
#pragma unroll
        for (int r = 0; r < 4; ++r) {
            const int row = 16 * mt + 4 * q + r;
            const float S = redS[0][row] + redS[1][row] + redS[2][row] + redS[3][row];
            const float Q = redQ[0][row] + redQ[1][row] + redQ[2][row] + redQ[3][row];
            const float m_ = S * (1.f / 128.f);
            const float iv = rsqrtf(Q * (1.f / 128.f) - m_ * m_ + 1e-5f);
#pragma unroll
            for (int nt = 0; nt < 2; ++nt) {
                const int col = wv * 32 + 16 * nt + c16;
                const float o = fmaxf((acc2[mt][nt][r] - m_) * iv * g2v[nt] + be2v[nt], 0.f);
                out_se[(size_t)(e0 + row) * 128 + col] = o;
            }
        }
}

extern "C" void kernel_launch(void* const* d_in, const int* in_sizes, int n_in,
                              void* d_out, int out_size, void* d_ws, size_t ws_size,
                              hipStream_t stream) {
    const float* nodes = (const float*)d_in[0];
    const int* clusters = (const int*)d_in[1];
    const int* bsrc = (const int*)d_in[2];
    const int* bdst = (const int*)d_in[3];
    const int* susrc = (const int*)d_in[4];
    const int* sudst = (const int*)d_in[5];
    const float* cW1 = (const float*)d_in[6];
    const float* cb1 = (const float*)d_in[7];
    const float* cg1 = (const float*)d_in[8];
    const float* cbe1 = (const float*)d_in[9];
    const float* cW2 = (const float*)d_in[10];
    const float* cb2 = (const float*)d_in[11];
    const float* eW1 = (const float*)d_in[12];
    const float* eb1 = (const float*)d_in[13];
    const float* eg1 = (const float*)d_in[14];
    const float* ebe1 = (const float*)d_in[15];
    const float* eW2 = (const float*)d_in[16];
    const float* eb2 = (const float*)d_in[17];
    const float* eg2 = (const float*)d_in[18];
    const float* ebe2 = (const float*)d_in[19];

    float* out_sn = (float*)d_out;
    float* out_se = out_sn + (size_t)CC * 128;
    float* out_bip = out_se + (size_t)ESN * 128;
    float* out_satt = out_bip + EBN;

    // workspace layout (u32 units)
    float* sums = (float*)d_ws;                            // 32000
    float* cnt = sums + 32000;                             // 2000
    int* hist = (int*)(cnt + 2000);                        // 2000
    unsigned* smax = (unsigned*)(hist + 2000);             // 2000
    float* asum = (float*)(smax + 2000);                   // 200000
    unsigned* amax = (unsigned*)(asum + 200000);           // 200000
    unsigned* amin = amax + 200000;                        // 200000
    unsigned* smin = amin + 200000;                        // 2000
    float* emb = (float*)(smin + 2000);                    // 3200000
    float* means = emb + 3200000;                          // 32000
    int* offs = (int*)(means + 32000);                     // 2000
    int* cursor = offs + 2000;                             // 2000
    int* src_sorted = cursor + 2000;                       // 2000000
    float* w_sorted = (float*)(src_sorted + 2000000);      // 2000000
    ushort_t* cW1hi = (ushort_t*)(w_sorted + 2000000);     // 65536 bf16
    ushort_t* cW1lo = cW1hi + 512 * 128;                   // 65536
    ushort_t* cW2hi = cW1lo + 512 * 128;                   // 8192
    ushort_t* cW2lo = cW2hi + 16 * 512;                    // 8192
    ushort_t* eW1t = cW2lo + 16 * 512;                     // 131072
    ushort_t* eW2t = eW1t + 512 * 256;                     // 65536

    // init: [sums|cnt|hist|smax|asum|amax] = 0 ; [amin|smin] = 0xFF
    hipMemsetAsync(sums, 0, (size_t)(32000 + 2000 + 2000 + 2000 + 200000 + 200000) * 4, stream);
    hipMemsetAsync(amin, 0xFF, (size_t)(200000 + 2000) * 4, stream);

    k_conv<<<1056, 256, 0, stream>>>(cW1, cW2, eW1, eW2, cW1hi, cW1lo, cW2hi, cW2lo, eW1t, eW2t);
    k_hist<<<256, 256, 0, stream>>>(bdst, hist);
    k_scan<<<1, 1024, 0, stream>>>(hist, offs, cursor);
    k_mlp1<<<NN / 32, 256, 0, stream>>>(nodes, clusters, cW1hi, cW1lo, cb1, cg1, cbe1, cW2hi, cW2lo, cb2, emb, sums, cnt);
    k_means<<<(CC * 16) / 256, 256, 0, stream>>>(sums, cnt, means);
    k_bip_dot<<<(EBN + 255) / 256, 256, 0, stream>>>(bsrc, bdst, emb, means, out_bip, amax, amin);
    k_bip_exp<<<(EBN + 255) / 256, 256, 0, stream>>>(bsrc, out_bip, amax, amin, asum);
    k_bip_scatter<<<(EBN + 255) / 256, 256, 0, stream>>>(bsrc, bdst, out_bip, asum, cursor, src_sorted, w_sorted);
    k_supernode<<<CC, 128, 0, stream>>>(src_sorted, w_sorted, offs, hist, nodes, out_sn);
    k_sup_dot<<<(ESN + 255) / 256, 256, 0, stream>>>(susrc, sudst, means, out_satt, smax, smin);
    k_sup_tanh<<<(ESN + 255) / 256, 256, 0, stream>>>(sudst, out_satt, smax, smin);
    k_edge_mlp<<<ESN / 32, 256, 0, stream>>>(susrc, sudst, out_sn, eW1t, eb1, eg1, ebe1, eW2t, eb2, eg2, ebe2, out_se);
}